// Round 6
// baseline (16927.448 us; speedup 1.0000x reference)
//
#include <hip/hip_runtime.h>

// ---------------------------------------------------------------------------
// Persistent weight-stationary LSTM, bf16 MFMA, narrow-span dataflow sync.
// T=1024 B=64 C=256 H=512, 2 layers, fp32 in/out.
//  - 64 blocks x 256 threads: blocks 0..31 = layer0, 32..63 = layer1.
//    Block = ALL 64 batches x 4 col-groups; wave = 1 cg, full K in VGPR
//    (L0: 24 frags = 96 VGPR, L1: 32 frags = 128 VGPR).
//  - Per tick, each block stages the full 64-row A-operand ONCE into LDS
//    (reg-staged relaxed-agent loads = MALL-coherent, proven r1/r2/r4) and
//    4 waves share it. L0: staging loads issued first, xproj MFMAs overlap
//    the RTT. L1: h1 loads issued AFTER the y0-tile barrier so the barrier's
//    vmcnt drain can't serialize them; they land under the y0 MFMAs.
//  - LDS: b128 row-linear writes (8-lane groups tile all 32 banks ->
//    conflict-free; fixes r4's 1.0e8 SQ_LDS_BANK_CONFLICT), pitch 520 u16.
//  - Sync: per-block monotonic flags (plain agent stores), one wave-wide poll
//    (64 lanes = 64 flags) covers both layers. h0 ring depth 4 decouples
//    layers. POLLS ARE BOUNDED: a wedge terminates with garbage (verify-fail)
//    instead of hanging the GPU/container (r5 lesson).
//  - out/final-state stores (plain, cached) AFTER flag publish.
// ---------------------------------------------------------------------------

#define TT 1024
#define BB 64
#define CC 256
#define HH 512
#define Y_ELEMS (TT * BB * HH)
#define S_ELEMS (BB * HH)
#define RING 4
#define POLL_MAX 16384

typedef __attribute__((ext_vector_type(8))) short bf16x8;
typedef __attribute__((ext_vector_type(4))) float f32x4;
typedef unsigned int u32;
typedef unsigned short u16;
typedef unsigned long long u64;

// ---- ws layout (bytes) ----
#define WS_CNT   0         // 64 flag lines * 64B: [0..31]=L0 blocks, [32..63]=L1
#define WS_BSUM0 4096      // 2048 f32
#define WS_BSUM1 12288     // 2048 f32
#define WS_H0R   20480     // RING * 65536 B (h0 ring, bf16; doubles as y0 feed)
#define WS_H1R   282624    // 2 * 65536 B  (h1 ping-pong, bf16)
#define WS_WPK0  413696    // 128*24*64*8 bf16 = 3145728 B
#define WS_WPK1  3559424   // 128*32*64*8 bf16 = 4194304 B
// end 7753728 (~7.75 MB)

__device__ __forceinline__ u16 f2b_rne(float f) {
    u32 u = __float_as_uint(f);
    return (u16)((u + 0x7FFFu + ((u >> 16) & 1u)) >> 16);
}
__device__ __forceinline__ u16 f2b_fast(float f) {  // round-half-up, 2 ops
    return (u16)((__float_as_uint(f) + 0x8000u) >> 16);
}
__device__ __forceinline__ float sigf(float z) { return 1.0f / (1.0f + __expf(-z)); }
__device__ __forceinline__ float tanh_f(float z) { return 2.0f / (1.0f + __expf(-2.0f * z)) - 1.0f; }

__device__ __forceinline__ bf16x8 pack8(float4 a, float4 b) {
    union { u16 u[8]; bf16x8 v; } r;
    r.u[0] = f2b_fast(a.x); r.u[1] = f2b_fast(a.y); r.u[2] = f2b_fast(a.z); r.u[3] = f2b_fast(a.w);
    r.u[4] = f2b_fast(b.x); r.u[5] = f2b_fast(b.y); r.u[6] = f2b_fast(b.z); r.u[7] = f2b_fast(b.w);
    return r.v;
}

// ---- MALL (agent, relaxed) accessors: the ONLY cross-block primitives ----
__device__ __forceinline__ u64 cload64(const u64* p) {
    return __hip_atomic_load((u64*)p, __ATOMIC_RELAXED, __HIP_MEMORY_SCOPE_AGENT);
}
__device__ __forceinline__ u32 cload32(const u32* p) {
    return __hip_atomic_load((u32*)p, __ATOMIC_RELAXED, __HIP_MEMORY_SCOPE_AGENT);
}
__device__ __forceinline__ void cstore64(u64* p, u64 v) {
    __hip_atomic_store(p, v, __ATOMIC_RELAXED, __HIP_MEMORY_SCOPE_AGENT);
}
__device__ __forceinline__ void cstore32(u32* p, u32 v) {
    __hip_atomic_store(p, v, __ATOMIC_RELAXED, __HIP_MEMORY_SCOPE_AGENT);
}

// One wave-wide poll for both layers' block flags (64B-spread lines).
// lane b      (b<32)  -> L0 block b   vs need0
// lane 32+b   (b<32)  -> L1 block b   vs need1
// BOUNDED: escapes after POLL_MAX iterations (deadlock => fast garbage finish
// + verify-fail, never a GPU hang).
__device__ __forceinline__ void poll2(const u32* cnt, u32 need0, u32 need1) {
    const int lane = threadIdx.x & 63;
    const u32* p = cnt + lane * 16;
    const u32 need = (lane < 32) ? need0 : need1;
    for (int it = 0; it < POLL_MAX; ++it) {
        if (__all((int)(cload32(p) >= need))) break;
        __builtin_amdgcn_s_sleep(1);
    }
    asm volatile("" ::: "memory");  // keep staging loads below the poll
}

// Gate epilogue: gather i,f,g,o for this lane's (batch,col) via shuffles.
__device__ __forceinline__ float lstm_cell(const f32x4 acc, int sl0, int sl1, int sl2, int sl3,
                                           int gg, float bi, float bf_, float bg_, float bo,
                                           float& c) {
    float gi = 0.f, gf = 0.f, gc = 0.f, go = 0.f;
    #pragma unroll
    for (int r = 0; r < 4; ++r) {
        float v0 = __shfl(acc[r], sl0, 64);
        float v1 = __shfl(acc[r], sl1, 64);
        float v2 = __shfl(acc[r], sl2, 64);
        float v3 = __shfl(acc[r], sl3, 64);
        if (r == gg) { gi = v0; gf = v1; gc = v2; go = v3; }
    }
    gi = sigf(gi + bi);
    gf = sigf(gf + bf_);
    gc = tanh_f(gc + bg_);
    go = sigf(go + bo);
    c = gf * c + gi * gc;
    return go * tanh_f(c);
}

// ---- init: zero flags, bsum = bih+bhh, h inits into ring slots ----
__global__ void k_init(const float* __restrict__ bih0, const float* __restrict__ bhh0,
                       const float* __restrict__ bih1, const float* __restrict__ bhh1,
                       const float* __restrict__ h00, const float* __restrict__ h01,
                       unsigned char* __restrict__ ws) {
    float* bs0 = (float*)(ws + WS_BSUM0);
    float* bs1 = (float*)(ws + WS_BSUM1);
    u16* h0 = (u16*)(ws + WS_H0R) + (RING - 1) * S_ELEMS;  // tick 0 reads slot 3
    u16* h1 = (u16*)(ws + WS_H1R) + S_ELEMS;               // tick 0 reads slot 1
    int t = blockIdx.x * 256 + threadIdx.x;  // 32768 threads
    if (t < 1024) ((u32*)ws)[t] = 0u;
    if (t < 2048) { bs0[t] = bih0[t] + bhh0[t]; bs1[t] = bih1[t] + bhh1[t]; }
    if (t < S_ELEMS) { h0[t] = f2b_rne(h00[t]); h1[t] = f2b_rne(h01[t]); }
}

// ---- weight pack: fp32 [4H,K] -> bf16 B-frag order wpk[cg][kt][lane][8] ----
// rows permuted: n-index (lane&15) = gg*4+jj  <->  W row = gg*512 + cg*4 + jj
// layer0: kt 0..7 = Wih0, 8..23 = Whh0. layer1: kt 0..15 = Wih1, 16..31 = Whh1.
__global__ void k_wprep(const float* __restrict__ Wih0, const float* __restrict__ Whh0,
                        const float* __restrict__ Wih1, const float* __restrict__ Whh1,
                        unsigned char* __restrict__ ws) {
    u16* wpk0 = (u16*)(ws + WS_WPK0);
    u16* wpk1 = (u16*)(ws + WS_WPK1);
    int u = blockIdx.x * 256 + threadIdx.x;  // 458752 threads
    const float* s;
    u16* d;
    if (u < 128 * 24 * 64) {
        int cg = u / (24 * 64);
        int kt = (u >> 6) % 24;
        int lane = u & 63;
        int n = lane & 15, quad = lane >> 4;
        int row = (n >> 2) * 512 + cg * 4 + (n & 3);
        int k = kt * 32 + quad * 8;
        s = (k < 256) ? (Wih0 + (size_t)row * 256 + k) : (Whh0 + (size_t)row * 512 + (k - 256));
        d = wpk0 + (size_t)((cg * 24 + kt) * 64 + lane) * 8;
    } else {
        int v = u - 128 * 24 * 64;
        int cg = v / (32 * 64);
        int kt = (v >> 6) % 32;
        int lane = v & 63;
        int n = lane & 15, quad = lane >> 4;
        int row = (n >> 2) * 512 + cg * 4 + (n & 3);
        int k = kt * 32 + quad * 8;
        s = (k < 512) ? (Wih1 + (size_t)row * 512 + k) : (Whh1 + (size_t)row * 512 + (k - 512));
        d = wpk1 + (size_t)((cg * 32 + kt) * 64 + lane) * 8;
    }
    #pragma unroll
    for (int i = 0; i < 8; ++i) d[i] = f2b_rne(s[i]);
}

// ---- dependency protocol (flag[b] = ticks completed, monotonic) ----
//  L0 tick t: all L0 >= t (h0[t-1] written); t>=4: all L1 >= t-3 (slot free)
//  L1 tick t: all L0 >= t+1 (y0[t] written); all L1 >= t (h1[t-1] written)

// ============================ layer 0 (32 blocks) ==========================
__device__ void run_l0(const float* __restrict__ x, const float* __restrict__ c0,
                       float* __restrict__ out, unsigned char* __restrict__ ws,
                       int bid, u16* smem) {
    u32* cnt = (u32*)(ws + WS_CNT);
    const float* bs = (const float*)(ws + WS_BSUM0);
    u16* h0r = (u16*)(ws + WS_H0R);
    const u16* wpk = (const u16*)(ws + WS_WPK0);

    const int tid = threadIdx.x, lane = tid & 63, wv = tid >> 6;
    const int r16 = lane & 15, quad = lane >> 4, q8 = quad * 8;
    const int gg = r16 >> 2, jj = r16 & 3;
    const int sl0 = (quad << 4) | jj, sl1 = sl0 | 4, sl2 = sl0 | 8, sl3 = sl0 | 12;
    const int cg = bid * 4 + wv;    // this wave's col-group (0..127)
    const int col = cg * 4 + jj;

    const float bi = bs[0 * HH + col], bff = bs[1 * HH + col];
    const float bgc = bs[2 * HH + col], bo = bs[3 * HH + col];
    float c[4];
    #pragma unroll
    for (int mt = 0; mt < 4; ++mt)
        c[mt] = c0[(mt * 16 + quad * 4 + gg) * HH + col];

    bf16x8 w[24];
    {
        const u16* wp = wpk + (size_t)(cg * 24 * 64 + lane) * 8;
        #pragma unroll
        for (int kt = 0; kt < 24; ++kt) w[kt] = *(const bf16x8*)(wp + (size_t)kt * 64 * 8);
    }

    for (int t = 0; t < TT; ++t) {
        if (t) poll2(cnt, (u32)t, (t >= RING) ? (u32)(t - RING + 1) : 0u);
        // issue ALL staging loads first (h0[t-1], ring slot (t-1)%4)
        const u64* src = (const u64*)(h0r + (size_t)((t + RING - 1) & (RING - 1)) * S_ELEMS);
        u64 sb[32];
        #pragma unroll
        for (int i = 0; i < 16; ++i) {
            int ch = i * 256 + tid;
            sb[2 * i]     = cload64(src + ch * 2);
            sb[2 * i + 1] = cload64(src + ch * 2 + 1);
        }
        // xproj MFMAs overlap the MALL RTT (independent of recurrence)
        f32x4 aE[4], aO[4];
        #pragma unroll
        for (int mt = 0; mt < 4; ++mt) {
            aE[mt] = (f32x4){0.f, 0.f, 0.f, 0.f};
            aO[mt] = (f32x4){0.f, 0.f, 0.f, 0.f};
        }
        #pragma unroll
        for (int mt = 0; mt < 4; ++mt) {
            const float* xp = x + ((size_t)t * BB + mt * 16 + r16) * CC + q8;
            #pragma unroll
            for (int kt = 0; kt < 8; ++kt) {
                float4 f0 = *(const float4*)(xp + kt * 32);
                float4 f1 = *(const float4*)(xp + kt * 32 + 4);
                bf16x8 a = pack8(f0, f1);
                if (kt & 1) aO[mt] = __builtin_amdgcn_mfma_f32_16x16x32_bf16(a, w[kt], aO[mt], 0, 0, 0);
                else        aE[mt] = __builtin_amdgcn_mfma_f32_16x16x32_bf16(a, w[kt], aE[mt], 0, 0, 0);
            }
        }
        // LDS tile write: b128 row-linear (8-lane groups tile 32 banks, clean)
        #pragma unroll
        for (int i = 0; i < 16; ++i) {
            int ch = i * 256 + tid;
            union { u64 q[2]; bf16x8 v; } u;
            u.q[0] = sb[2 * i]; u.q[1] = sb[2 * i + 1];
            *(bf16x8*)&smem[(ch >> 6) * 520 + (ch & 63) * 8] = u.v;
        }
        __syncthreads();
        // recurrence MFMAs from LDS (shared by 4 waves)
        #pragma unroll
        for (int kt = 0; kt < 16; ++kt)
            #pragma unroll
            for (int mt = 0; mt < 4; ++mt) {
                bf16x8 a = *(const bf16x8*)&smem[(mt * 16 + r16) * 520 + kt * 32 + q8];
                if (kt & 1) aO[mt] = __builtin_amdgcn_mfma_f32_16x16x32_bf16(a, w[8 + kt], aO[mt], 0, 0, 0);
                else        aE[mt] = __builtin_amdgcn_mfma_f32_16x16x32_bf16(a, w[8 + kt], aE[mt], 0, 0, 0);
            }
        // epilogue: gates -> h store (agent, MALL)
        u16* hw = h0r + (size_t)(t & (RING - 1)) * S_ELEMS;
        float hs[4];
        #pragma unroll
        for (int mt = 0; mt < 4; ++mt) {
            f32x4 acc = aE[mt] + aO[mt];
            float h = lstm_cell(acc, sl0, sl1, sl2, sl3, gg, bi, bff, bgc, bo, c[mt]);
            hs[mt] = h;
            int myb = mt * 16 + quad * 4 + gg;
            u32 hb = (u32)f2b_rne(h);
            u32 v01 = hb | ((u32)__shfl_xor((int)hb, 1, 64) << 16);
            u32 v23 = (u32)__shfl_xor((int)v01, 2, 64);
            if (jj == 0)
                cstore64((u64*)(hw + (size_t)myb * HH + cg * 4), (u64)v01 | ((u64)v23 << 32));
        }
        __syncthreads();  // drains all waves' vmcnt -> h stores at MALL
        if (tid == 0) cstore32(cnt + bid * 16, (u32)(t + 1));
        if (t == TT - 1) {  // final state, plain stores, off critical path
            float* fin = out + Y_ELEMS;
            #pragma unroll
            for (int mt = 0; mt < 4; ++mt) {
                int myb = mt * 16 + quad * 4 + gg;
                fin[myb * HH + col] = hs[mt];
                fin[S_ELEMS + myb * HH + col] = c[mt];
            }
        }
    }
}

// ============================ layer 1 (32 blocks) ==========================
__device__ void run_l1(const float* __restrict__ c0, float* __restrict__ out,
                       unsigned char* __restrict__ ws, int bid, u16* smem) {
    u32* cnt = (u32*)(ws + WS_CNT);
    const float* bs = (const float*)(ws + WS_BSUM1);
    const u16* h0r = (const u16*)(ws + WS_H0R);
    u16* h1r = (u16*)(ws + WS_H1R);
    const u16* wpk = (const u16*)(ws + WS_WPK1);
    const int TILE1 = 64 * 520;

    const int tid = threadIdx.x, lane = tid & 63, wv = tid >> 6;
    const int r16 = lane & 15, quad = lane >> 4, q8 = quad * 8;
    const int gg = r16 >> 2, jj = r16 & 3;
    const int sl0 = (quad << 4) | jj, sl1 = sl0 | 4, sl2 = sl0 | 8, sl3 = sl0 | 12;
    const int cg = bid * 4 + wv;    // this wave's single col-group
    const int col = cg * 4 + jj;

    const float bi = bs[0 * HH + col], bff = bs[1 * HH + col];
    const float bgc = bs[2 * HH + col], bo = bs[3 * HH + col];
    float c[4];
    #pragma unroll
    for (int mt = 0; mt < 4; ++mt)
        c[mt] = c0[(mt * 16 + quad * 4 + gg) * HH + col];

    bf16x8 w[32];
    {
        const u16* wp = wpk + (size_t)(cg * 32 * 64 + lane) * 8;
        #pragma unroll
        for (int kt = 0; kt < 32; ++kt) w[kt] = *(const bf16x8*)(wp + (size_t)kt * 64 * 8);
    }

    for (int t = 0; t < TT; ++t) {
        poll2(cnt, (u32)(t + 1), (u32)t);
        // stage y0[t] (ring slot t%4) -> LDS tile 0
        const u64* sy = (const u64*)(h0r + (size_t)(t & (RING - 1)) * S_ELEMS);
        u64 yb[32];
        #pragma unroll
        for (int i = 0; i < 16; ++i) {
            int ch = i * 256 + tid;
            yb[2 * i]     = cload64(sy + ch * 2);
            yb[2 * i + 1] = cload64(sy + ch * 2 + 1);
        }
        #pragma unroll
        for (int i = 0; i < 16; ++i) {
            int ch = i * 256 + tid;
            union { u64 q[2]; bf16x8 v; } u;
            u.q[0] = yb[2 * i]; u.q[1] = yb[2 * i + 1];
            *(bf16x8*)&smem[(ch >> 6) * 520 + (ch & 63) * 8] = u.v;
        }
        __syncthreads();  // tile 0 visible (drain happens BEFORE h1 loads issue)
        // issue h1[t-1] loads now -> they fly under the y0 MFMAs
        const u64* sh = (const u64*)(h1r + (size_t)((t + 1) & 1) * S_ELEMS);
        u64 hb_[32];
        #pragma unroll
        for (int i = 0; i < 16; ++i) {
            int ch = i * 256 + tid;
            hb_[2 * i]     = cload64(sh + ch * 2);
            hb_[2 * i + 1] = cload64(sh + ch * 2 + 1);
        }
        f32x4 aE[4], aO[4];
        #pragma unroll
        for (int mt = 0; mt < 4; ++mt) {
            aE[mt] = (f32x4){0.f, 0.f, 0.f, 0.f};
            aO[mt] = (f32x4){0.f, 0.f, 0.f, 0.f};
        }
        #pragma unroll
        for (int kt = 0; kt < 16; ++kt)
            #pragma unroll
            for (int mt = 0; mt < 4; ++mt) {
                bf16x8 a = *(const bf16x8*)&smem[(mt * 16 + r16) * 520 + kt * 32 + q8];
                if (kt & 1) aO[mt] = __builtin_amdgcn_mfma_f32_16x16x32_bf16(a, w[kt], aO[mt], 0, 0, 0);
                else        aE[mt] = __builtin_amdgcn_mfma_f32_16x16x32_bf16(a, w[kt], aE[mt], 0, 0, 0);
            }
        // write h1 tile (vmcnt waits only for hb_, which landed during MFMAs)
        #pragma unroll
        for (int i = 0; i < 16; ++i) {
            int ch = i * 256 + tid;
            union { u64 q[2]; bf16x8 v; } u;
            u.q[0] = hb_[2 * i]; u.q[1] = hb_[2 * i + 1];
            *(bf16x8*)&smem[TILE1 + (ch >> 6) * 520 + (ch & 63) * 8] = u.v;
        }
        __syncthreads();  // tile 1 visible
        #pragma unroll
        for (int kt = 0; kt < 16; ++kt)
            #pragma unroll
            for (int mt = 0; mt < 4; ++mt) {
                bf16x8 a = *(const bf16x8*)&smem[TILE1 + (mt * 16 + r16) * 520 + kt * 32 + q8];
                if (kt & 1) aO[mt] = __builtin_amdgcn_mfma_f32_16x16x32_bf16(a, w[16 + kt], aO[mt], 0, 0, 0);
                else        aE[mt] = __builtin_amdgcn_mfma_f32_16x16x32_bf16(a, w[16 + kt], aE[mt], 0, 0, 0);
            }
        // epilogue
        u16* hw = h1r + (size_t)(t & 1) * S_ELEMS;
        float hs[4];
        #pragma unroll
        for (int mt = 0; mt < 4; ++mt) {
            f32x4 acc = aE[mt] + aO[mt];
            float h = lstm_cell(acc, sl0, sl1, sl2, sl3, gg, bi, bff, bgc, bo, c[mt]);
            hs[mt] = h;
            int myb = mt * 16 + quad * 4 + gg;
            u32 hb = (u32)f2b_rne(h);
            u32 v01 = hb | ((u32)__shfl_xor((int)hb, 1, 64) << 16);
            u32 v23 = (u32)__shfl_xor((int)v01, 2, 64);
            if (jj == 0)
                cstore64((u64*)(hw + (size_t)myb * HH + cg * 4), (u64)v01 | ((u64)v23 << 32));
        }
        __syncthreads();  // drains vmcnt -> h1 stores at MALL
        if (tid == 0) cstore32(cnt + (32 + bid) * 16, (u32)(t + 1));
        // out stores (plain, cached) AFTER publish - off the critical path
        #pragma unroll
        for (int mt = 0; mt < 4; ++mt) {
            int myb = mt * 16 + quad * 4 + gg;
            out[(size_t)t * S_ELEMS + myb * HH + col] = hs[mt];
        }
        if (t == TT - 1) {
            float* fin = out + Y_ELEMS + 2 * S_ELEMS;
            #pragma unroll
            for (int mt = 0; mt < 4; ++mt) {
                int myb = mt * 16 + quad * 4 + gg;
                fin[myb * HH + col] = hs[mt];
                fin[S_ELEMS + myb * HH + col] = c[mt];
            }
        }
    }
}

__global__ __launch_bounds__(256, 1) void k_lstm(const float* __restrict__ x,
                                                 const float* __restrict__ c00,
                                                 const float* __restrict__ c01,
                                                 float* __restrict__ out,
                                                 unsigned char* __restrict__ ws) {
    __shared__ __align__(16) u16 smem[2][64][520];  // 133120 B -> 1 block/CU
    const int bid = blockIdx.x;
    if (bid < 32) run_l0(x, c00, out, ws, bid, &smem[0][0][0]);
    else          run_l1(c01, out, ws, bid - 32, &smem[0][0][0]);
}

extern "C" void kernel_launch(void* const* d_in, const int* in_sizes, int n_in,
                              void* d_out, int out_size, void* d_ws, size_t ws_size,
                              hipStream_t stream) {
    const float* x    = (const float*)d_in[0];
    const float* h0_0 = (const float*)d_in[1];
    const float* c0_0 = (const float*)d_in[2];
    const float* h0_1 = (const float*)d_in[3];
    const float* c0_1 = (const float*)d_in[4];
    const float* Wih0 = (const float*)d_in[5];
    const float* Whh0 = (const float*)d_in[6];
    const float* bih0 = (const float*)d_in[7];
    const float* bhh0 = (const float*)d_in[8];
    const float* Wih1 = (const float*)d_in[9];
    const float* Whh1 = (const float*)d_in[10];
    const float* bih1 = (const float*)d_in[11];
    const float* bhh1 = (const float*)d_in[12];
    float* out = (float*)d_out;
    unsigned char* ws = (unsigned char*)d_ws;

    k_init<<<128, 256, 0, stream>>>(bih0, bhh0, bih1, bhh1, h0_0, h0_1, ws);
    k_wprep<<<1792, 256, 0, stream>>>(Wih0, Whh0, Wih1, Whh1, ws);
    k_lstm<<<64, 256, 0, stream>>>(x, c0_0, c0_1, out, ws);
}

// Round 7
// 6177.420 us; speedup vs baseline: 2.7402x; 2.7402x over previous
//
#include <hip/hip_runtime.h>

// ---------------------------------------------------------------------------
// Persistent weight-stationary LSTM, bf16 MFMA, decoupled per-layer sync.
// T=1024 B=64 C=256 H=512, 2 layers, fp32 in/out.
// == r4 structure (measured 6732 us) with de-contended sync ==
//  - 128 blocks x 256 threads: blocks 0..63 = layer0, 64..127 = layer1.
//    Block = 2 M-tiles (32 batches) x 4 column-groups; wave = 1 cg, full K.
//  - A-operands staged ONCE per block per tick into LDS (reg-staged relaxed
//    agent loads = MALL-coherent), shared by 4 waves. Pitch 520 u16.
//  - L0: xproj MFMAs BEFORE the poll (overlap the straggler window - r4's
//    ordering, proven; r6 lost this and regressed).
//  - SYNC (new): hierarchical publish - per-group atomic add returns prev;
//    the 8th finisher bumps a per-layer line. Pollers watch 2 lines (not 16),
//    same-address per wave => ~2 MALL requests/wave/round (~60x less poll
//    traffic; r2 lesson: poll traffic contends with awaited stores).
//    Polls BOUNDED (r5 lesson: wedge => garbage+verify-fail, not a dead node).
//  - out/final-state stores AFTER flag publish (off the vmcnt drain).
//  - NOTE: SQ_LDS_BANK_CONFLICT ~1.0e8 is ds_bpermute (lstm_cell shuffles),
//    structural, identical r4/r6 - not addressable via LDS layout.
// ---------------------------------------------------------------------------

#define TT 1024
#define BB 64
#define CC 256
#define HH 512
#define Y_ELEMS (TT * BB * HH)
#define S_ELEMS (BB * HH)
#define RING 4
#define POLL_MAX 16384

typedef __attribute__((ext_vector_type(8))) short bf16x8;
typedef __attribute__((ext_vector_type(4))) float f32x4;
typedef unsigned int u32;
typedef unsigned short u16;
typedef unsigned long long u64;

// ---- ws layout (bytes) ----
#define WS_CNT   0         // 1024 u32: [g*16] g<16 group counters; [256]=L0 layer line; [272]=L1
#define WS_BSUM0 4096      // 2048 f32
#define WS_BSUM1 12288     // 2048 f32
#define WS_H0R   20480     // RING * 65536 B (h0 ring, bf16; doubles as y0 feed)
#define WS_H1R   282624    // 2 * 65536 B  (h1 ping-pong, bf16)
#define WS_WPK0  413696    // 128*24*64*8 bf16 = 3145728 B
#define WS_WPK1  3559424   // 128*32*64*8 bf16 = 4194304 B
// end 7753728 (~7.75 MB)

__device__ __forceinline__ u16 f2b_rne(float f) {
    u32 u = __float_as_uint(f);
    return (u16)((u + 0x7FFFu + ((u >> 16) & 1u)) >> 16);
}
__device__ __forceinline__ u16 f2b_fast(float f) {  // round-half-up, 2 ops
    return (u16)((__float_as_uint(f) + 0x8000u) >> 16);
}
__device__ __forceinline__ float sigf(float z) { return 1.0f / (1.0f + __expf(-z)); }
__device__ __forceinline__ float tanh_f(float z) { return 2.0f / (1.0f + __expf(-2.0f * z)) - 1.0f; }

__device__ __forceinline__ bf16x8 pack8(float4 a, float4 b) {
    union { u16 u[8]; bf16x8 v; } r;
    r.u[0] = f2b_fast(a.x); r.u[1] = f2b_fast(a.y); r.u[2] = f2b_fast(a.z); r.u[3] = f2b_fast(a.w);
    r.u[4] = f2b_fast(b.x); r.u[5] = f2b_fast(b.y); r.u[6] = f2b_fast(b.z); r.u[7] = f2b_fast(b.w);
    return r.v;
}

// ---- MALL (agent, relaxed) accessors: the ONLY cross-block primitives ----
__device__ __forceinline__ u64 cload64(const u64* p) {
    return __hip_atomic_load((u64*)p, __ATOMIC_RELAXED, __HIP_MEMORY_SCOPE_AGENT);
}
__device__ __forceinline__ u32 cload32(const u32* p) {
    return __hip_atomic_load((u32*)p, __ATOMIC_RELAXED, __HIP_MEMORY_SCOPE_AGENT);
}
__device__ __forceinline__ void cstore64(u64* p, u64 v) {
    __hip_atomic_store(p, v, __ATOMIC_RELAXED, __HIP_MEMORY_SCOPE_AGENT);
}
__device__ __forceinline__ u32 cadd32(u32* p, u32 v) {
    return __hip_atomic_fetch_add(p, v, __ATOMIC_RELAXED, __HIP_MEMORY_SCOPE_AGENT);
}

// 2-line poll: lane parity picks the L0 or L1 layer line (same addr across the
// wave => coalesced single request per line). Bounded (deadlock => fast
// garbage finish + verify-fail, never a node-killing hang).
__device__ __forceinline__ void pollL(const u32* cnt, u32 need0, u32 need1) {
    const int odd = threadIdx.x & 1;
    const u32* p = cnt + (odd ? 272 : 256);
    const u32 need = odd ? need1 : need0;
    for (int it = 0; it < POLL_MAX; ++it) {
        if (__all((int)(cload32(p) >= need))) break;
        __builtin_amdgcn_s_sleep(1);
    }
    asm volatile("" ::: "memory");  // keep staging loads below the poll
}

// Hierarchical publish: group add (8 blocks/group); 8th finisher of the tick
// bumps the layer line. Layer line hits 8*(t+1) when all its blocks did tick t.
__device__ __forceinline__ void publish(u32* cnt, int group, int layerline, u32 t1) {
    u32 prev = cadd32(cnt + group * 16, 1u);
    if (prev == 8u * t1 - 1u) cadd32(cnt + layerline, 1u);
}

// Gate epilogue: gather i,f,g,o for this lane's (batch,col) via shuffles.
__device__ __forceinline__ float lstm_cell(const f32x4 acc, int sl0, int sl1, int sl2, int sl3,
                                           int gg, float bi, float bf_, float bg_, float bo,
                                           float& c) {
    float gi = 0.f, gf = 0.f, gc = 0.f, go = 0.f;
    #pragma unroll
    for (int r = 0; r < 4; ++r) {
        float v0 = __shfl(acc[r], sl0, 64);
        float v1 = __shfl(acc[r], sl1, 64);
        float v2 = __shfl(acc[r], sl2, 64);
        float v3 = __shfl(acc[r], sl3, 64);
        if (r == gg) { gi = v0; gf = v1; gc = v2; go = v3; }
    }
    gi = sigf(gi + bi);
    gf = sigf(gf + bf_);
    gc = tanh_f(gc + bg_);
    go = sigf(go + bo);
    c = gf * c + gi * gc;
    return go * tanh_f(c);
}

// ---- init: zero counters (incl. layer lines), bsum = bih+bhh, h inits ----
__global__ void k_init(const float* __restrict__ bih0, const float* __restrict__ bhh0,
                       const float* __restrict__ bih1, const float* __restrict__ bhh1,
                       const float* __restrict__ h00, const float* __restrict__ h01,
                       unsigned char* __restrict__ ws) {
    float* bs0 = (float*)(ws + WS_BSUM0);
    float* bs1 = (float*)(ws + WS_BSUM1);
    u16* h0 = (u16*)(ws + WS_H0R) + (RING - 1) * S_ELEMS;  // tick 0 reads slot 3
    u16* h1 = (u16*)(ws + WS_H1R) + S_ELEMS;               // tick 0 reads slot 1
    int t = blockIdx.x * 256 + threadIdx.x;  // 32768 threads
    if (t < 1024) ((u32*)ws)[t] = 0u;
    if (t < 2048) { bs0[t] = bih0[t] + bhh0[t]; bs1[t] = bih1[t] + bhh1[t]; }
    if (t < S_ELEMS) { h0[t] = f2b_rne(h00[t]); h1[t] = f2b_rne(h01[t]); }
}

// ---- weight pack: fp32 [4H,K] -> bf16 B-frag order wpk[cg][kt][lane][8] ----
// rows permuted: n-index (lane&15) = gg*4+jj  <->  W row = gg*512 + cg*4 + jj
// layer0: kt 0..7 = Wih0, 8..23 = Whh0. layer1: kt 0..15 = Wih1, 16..31 = Whh1.
__global__ void k_wprep(const float* __restrict__ Wih0, const float* __restrict__ Whh0,
                        const float* __restrict__ Wih1, const float* __restrict__ Whh1,
                        unsigned char* __restrict__ ws) {
    u16* wpk0 = (u16*)(ws + WS_WPK0);
    u16* wpk1 = (u16*)(ws + WS_WPK1);
    int u = blockIdx.x * 256 + threadIdx.x;  // 458752 threads
    const float* s;
    u16* d;
    if (u < 128 * 24 * 64) {
        int cg = u / (24 * 64);
        int kt = (u >> 6) % 24;
        int lane = u & 63;
        int n = lane & 15, quad = lane >> 4;
        int row = (n >> 2) * 512 + cg * 4 + (n & 3);
        int k = kt * 32 + quad * 8;
        s = (k < 256) ? (Wih0 + (size_t)row * 256 + k) : (Whh0 + (size_t)row * 512 + (k - 256));
        d = wpk0 + (size_t)((cg * 24 + kt) * 64 + lane) * 8;
    } else {
        int v = u - 128 * 24 * 64;
        int cg = v / (32 * 64);
        int kt = (v >> 6) % 32;
        int lane = v & 63;
        int n = lane & 15, quad = lane >> 4;
        int row = (n >> 2) * 512 + cg * 4 + (n & 3);
        int k = kt * 32 + quad * 8;
        s = (k < 512) ? (Wih1 + (size_t)row * 512 + k) : (Whh1 + (size_t)row * 512 + (k - 512));
        d = wpk1 + (size_t)((cg * 32 + kt) * 64 + lane) * 8;
    }
    #pragma unroll
    for (int i = 0; i < 8; ++i) d[i] = f2b_rne(s[i]);
}

// ---- dependency protocol (layer line = 8 * ticks-all-done, monotonic) ----
//  L0 tick t: L0 line >= 8t (h0[t-1] written); t>=4: L1 line >= 8(t-3)
//  L1 tick t: L0 line >= 8(t+1) (y0[t] written); L1 line >= 8t

// ============================ layer 0 (64 blocks) ==========================
__device__ void run_l0(const float* __restrict__ x, const float* __restrict__ c0,
                       float* __restrict__ out, unsigned char* __restrict__ ws,
                       int bid, u16* smem) {
    u32* cnt = (u32*)(ws + WS_CNT);
    const float* bs = (const float*)(ws + WS_BSUM0);
    u16* h0r = (u16*)(ws + WS_H0R);
    const u16* wpk = (const u16*)(ws + WS_WPK0);

    const int tid = threadIdx.x, lane = tid & 63, wv = tid >> 6;
    const int mg = bid & 1;               // M-group: batches mg*32 .. mg*32+31
    const int cg = (bid >> 1) * 4 + wv;   // this wave's column-group (0..127)
    const int r16 = lane & 15, quad = lane >> 4, q8 = quad * 8;
    const int gg = r16 >> 2, jj = r16 & 3;
    const int sl0 = (quad << 4) | jj, sl1 = sl0 | 4, sl2 = sl0 | 8, sl3 = sl0 | 12;
    const int col = cg * 4 + jj;

    const float bi = bs[0 * HH + col], bff = bs[1 * HH + col];
    const float bgc = bs[2 * HH + col], bo = bs[3 * HH + col];
    float c[2];
    #pragma unroll
    for (int mt = 0; mt < 2; ++mt)
        c[mt] = c0[(mg * 32 + mt * 16 + quad * 4 + gg) * HH + col];

    bf16x8 w[24];
    {
        const u16* wp = wpk + (size_t)(cg * 24 * 64 + lane) * 8;
        #pragma unroll
        for (int kt = 0; kt < 24; ++kt) w[kt] = *(const bf16x8*)(wp + (size_t)kt * 64 * 8);
    }

    for (int t = 0; t < TT; ++t) {
        f32x4 aE[2] = {{0.f,0.f,0.f,0.f},{0.f,0.f,0.f,0.f}};
        f32x4 aO[2] = {{0.f,0.f,0.f,0.f},{0.f,0.f,0.f,0.f}};
        // x projection FIRST (independent of recurrence -> overlaps peers'
        // straggler window; r4 ordering, load x while others finish)
        #pragma unroll
        for (int mt = 0; mt < 2; ++mt) {
            const float* xp = x + ((size_t)t * BB + mg * 32 + mt * 16 + r16) * CC + q8;
            #pragma unroll
            for (int kt = 0; kt < 8; ++kt) {
                float4 f0 = *(const float4*)(xp + kt * 32);
                float4 f1 = *(const float4*)(xp + kt * 32 + 4);
                bf16x8 a = pack8(f0, f1);
                if (kt & 1) aO[mt] = __builtin_amdgcn_mfma_f32_16x16x32_bf16(a, w[kt], aO[mt], 0, 0, 0);
                else        aE[mt] = __builtin_amdgcn_mfma_f32_16x16x32_bf16(a, w[kt], aE[mt], 0, 0, 0);
            }
        }
        if (t) pollL(cnt, 8u * (u32)t, (t >= RING) ? 8u * (u32)(t - RING + 1) : 0u);
        // stage h0[t-1] slice (32 rows) into LDS
        {
            const u64* srcq = (const u64*)(h0r + (size_t)((t + RING - 1) & (RING - 1)) * S_ELEMS
                                           + (size_t)mg * 32 * HH);
            u64 sb[16];
            #pragma unroll
            for (int i = 0; i < 8; ++i) {
                int ch = i * 256 + tid;
                sb[2 * i]     = cload64(srcq + ch * 2);
                sb[2 * i + 1] = cload64(srcq + ch * 2 + 1);
            }
            #pragma unroll
            for (int i = 0; i < 8; ++i) {
                int ch = i * 256 + tid;
                union { u64 q[2]; bf16x8 v; } u;
                u.q[0] = sb[2 * i]; u.q[1] = sb[2 * i + 1];
                *(bf16x8*)&smem[(ch >> 6) * 520 + (ch & 63) * 8] = u.v;
            }
        }
        __syncthreads();
        // recurrent MFMAs from LDS (shared by all 4 waves)
        #pragma unroll
        for (int kt = 0; kt < 16; ++kt)
            #pragma unroll
            for (int mt = 0; mt < 2; ++mt) {
                bf16x8 a = *(const bf16x8*)&smem[(mt * 16 + r16) * 520 + kt * 32 + q8];
                if (kt & 1) aO[mt] = __builtin_amdgcn_mfma_f32_16x16x32_bf16(a, w[8 + kt], aO[mt], 0, 0, 0);
                else        aE[mt] = __builtin_amdgcn_mfma_f32_16x16x32_bf16(a, w[8 + kt], aE[mt], 0, 0, 0);
            }
        // epilogue: gates -> h store (agent, MALL)
        u16* hw = h0r + (size_t)(t & (RING - 1)) * S_ELEMS;
        float hs[2];
        #pragma unroll
        for (int mt = 0; mt < 2; ++mt) {
            f32x4 acc = aE[mt] + aO[mt];
            float h = lstm_cell(acc, sl0, sl1, sl2, sl3, gg, bi, bff, bgc, bo, c[mt]);
            hs[mt] = h;
            int myb = mg * 32 + mt * 16 + quad * 4 + gg;
            u32 hb = (u32)f2b_rne(h);
            u32 v01 = hb | ((u32)__shfl_xor((int)hb, 1, 64) << 16);
            u32 v23 = (u32)__shfl_xor((int)v01, 2, 64);
            if (jj == 0)
                cstore64((u64*)(hw + (size_t)myb * HH + cg * 4), (u64)v01 | ((u64)v23 << 32));
        }
        __syncthreads();  // drains all waves' vmcnt -> h stores at MALL
        if (tid == 0) publish(cnt, bid >> 3, 256, (u32)(t + 1));
        if (t == TT - 1) {  // final state, plain stores, post-publish
            float* fin = out + Y_ELEMS;
            #pragma unroll
            for (int mt = 0; mt < 2; ++mt) {
                int myb = mg * 32 + mt * 16 + quad * 4 + gg;
                fin[myb * HH + col] = hs[mt];
                fin[S_ELEMS + myb * HH + col] = c[mt];
            }
        }
    }
}

// ============================ layer 1 (64 blocks) ==========================
__device__ void run_l1(const float* __restrict__ c0, float* __restrict__ out,
                       unsigned char* __restrict__ ws, int b2, u16* smem) {
    u32* cnt = (u32*)(ws + WS_CNT);
    const float* bs = (const float*)(ws + WS_BSUM1);
    const u16* h0r = (const u16*)(ws + WS_H0R);
    u16* h1r = (u16*)(ws + WS_H1R);
    const u16* wpk = (const u16*)(ws + WS_WPK1);
    const int TILE1 = 32 * 520;

    const int tid = threadIdx.x, lane = tid & 63, wv = tid >> 6;
    const int mg = b2 & 1;
    const int cg = (b2 >> 1) * 4 + wv;
    const int r16 = lane & 15, quad = lane >> 4, q8 = quad * 8;
    const int gg = r16 >> 2, jj = r16 & 3;
    const int sl0 = (quad << 4) | jj, sl1 = sl0 | 4, sl2 = sl0 | 8, sl3 = sl0 | 12;
    const int col = cg * 4 + jj;

    const float bi = bs[0 * HH + col], bff = bs[1 * HH + col];
    const float bgc = bs[2 * HH + col], bo = bs[3 * HH + col];
    float c[2];
    #pragma unroll
    for (int mt = 0; mt < 2; ++mt)
        c[mt] = c0[(mg * 32 + mt * 16 + quad * 4 + gg) * HH + col];

    bf16x8 w[32];
    {
        const u16* wp = wpk + (size_t)(cg * 32 * 64 + lane) * 8;
        #pragma unroll
        for (int kt = 0; kt < 32; ++kt) w[kt] = *(const bf16x8*)(wp + (size_t)kt * 64 * 8);
    }

    for (int t = 0; t < TT; ++t) {
        pollL(cnt, 8u * (u32)(t + 1), t ? 8u * (u32)t : 0u);
        // phase A: stage y0[t] slice (ring slot t%4) -> LDS tile 0
        {
            const u64* sy = (const u64*)(h0r + (size_t)(t & (RING - 1)) * S_ELEMS
                                         + (size_t)mg * 32 * HH);
            u64 sb[16];
            #pragma unroll
            for (int i = 0; i < 8; ++i) {
                int ch = i * 256 + tid;
                sb[2 * i]     = cload64(sy + ch * 2);
                sb[2 * i + 1] = cload64(sy + ch * 2 + 1);
            }
            #pragma unroll
            for (int i = 0; i < 8; ++i) {
                int ch = i * 256 + tid;
                union { u64 q[2]; bf16x8 v; } u;
                u.q[0] = sb[2 * i]; u.q[1] = sb[2 * i + 1];
                *(bf16x8*)&smem[(ch >> 6) * 520 + (ch & 63) * 8] = u.v;
            }
        }
        // phase B: ISSUE h1[t-1] loads now; they drain with the barrier below
        u64 hc[16];
        {
            const u64* sh = (const u64*)(h1r + (size_t)((t + 1) & 1) * S_ELEMS
                                         + (size_t)mg * 32 * HH);
            #pragma unroll
            for (int i = 0; i < 8; ++i) {
                int ch = i * 256 + tid;
                hc[2 * i]     = cload64(sh + ch * 2);
                hc[2 * i + 1] = cload64(sh + ch * 2 + 1);
            }
        }
        __syncthreads();  // tile 0 visible
        f32x4 aE[2] = {{0.f,0.f,0.f,0.f},{0.f,0.f,0.f,0.f}};
        f32x4 aO[2] = {{0.f,0.f,0.f,0.f},{0.f,0.f,0.f,0.f}};
        #pragma unroll
        for (int kt = 0; kt < 16; ++kt)
            #pragma unroll
            for (int mt = 0; mt < 2; ++mt) {
                bf16x8 a = *(const bf16x8*)&smem[(mt * 16 + r16) * 520 + kt * 32 + q8];
                if (kt & 1) aO[mt] = __builtin_amdgcn_mfma_f32_16x16x32_bf16(a, w[kt], aO[mt], 0, 0, 0);
                else        aE[mt] = __builtin_amdgcn_mfma_f32_16x16x32_bf16(a, w[kt], aE[mt], 0, 0, 0);
            }
        // write h1 tile (loads already landed)
        #pragma unroll
        for (int i = 0; i < 8; ++i) {
            int ch = i * 256 + tid;
            union { u64 q[2]; bf16x8 v; } u;
            u.q[0] = hc[2 * i]; u.q[1] = hc[2 * i + 1];
            *(bf16x8*)&smem[TILE1 + (ch >> 6) * 520 + (ch & 63) * 8] = u.v;
        }
        __syncthreads();  // tile 1 visible
        #pragma unroll
        for (int kt = 0; kt < 16; ++kt)
            #pragma unroll
            for (int mt = 0; mt < 2; ++mt) {
                bf16x8 a = *(const bf16x8*)&smem[TILE1 + (mt * 16 + r16) * 520 + kt * 32 + q8];
                if (kt & 1) aO[mt] = __builtin_amdgcn_mfma_f32_16x16x32_bf16(a, w[16 + kt], aO[mt], 0, 0, 0);
                else        aE[mt] = __builtin_amdgcn_mfma_f32_16x16x32_bf16(a, w[16 + kt], aE[mt], 0, 0, 0);
            }
        // epilogue
        u16* hw = h1r + (size_t)(t & 1) * S_ELEMS;
        float hs[2];
        #pragma unroll
        for (int mt = 0; mt < 2; ++mt) {
            f32x4 acc = aE[mt] + aO[mt];
            float h = lstm_cell(acc, sl0, sl1, sl2, sl3, gg, bi, bff, bgc, bo, c[mt]);
            hs[mt] = h;
            int myb = mg * 32 + mt * 16 + quad * 4 + gg;
            u32 hb = (u32)f2b_rne(h);
            u32 v01 = hb | ((u32)__shfl_xor((int)hb, 1, 64) << 16);
            u32 v23 = (u32)__shfl_xor((int)v01, 2, 64);
            if (jj == 0)
                cstore64((u64*)(hw + (size_t)myb * HH + cg * 4), (u64)v01 | ((u64)v23 << 32));
        }
        __syncthreads();  // drains vmcnt -> h1 stores at MALL
        if (tid == 0) publish(cnt, 8 + (b2 >> 3), 272, (u32)(t + 1));
        // out stores (plain, cached) AFTER publish - off the critical path
        #pragma unroll
        for (int mt = 0; mt < 2; ++mt) {
            int myb = mg * 32 + mt * 16 + quad * 4 + gg;
            out[(size_t)t * S_ELEMS + myb * HH + col] = hs[mt];
        }
        if (t == TT - 1) {
            float* fin = out + Y_ELEMS + 2 * S_ELEMS;
            #pragma unroll
            for (int mt = 0; mt < 2; ++mt) {
                int myb = mg * 32 + mt * 16 + quad * 4 + gg;
                fin[myb * HH + col] = hs[mt];
                fin[S_ELEMS + myb * HH + col] = c[mt];
            }
        }
    }
}

__global__ __launch_bounds__(256, 1) void k_lstm(const float* __restrict__ x,
                                                 const float* __restrict__ c00,
                                                 const float* __restrict__ c01,
                                                 float* __restrict__ out,
                                                 unsigned char* __restrict__ ws) {
    __shared__ __align__(16) u16 smem[2][32][520];  // 66560 B (r4 footprint)
    const int bid = blockIdx.x;
    if (bid < 64) run_l0(x, c00, out, ws, bid, &smem[0][0][0]);
    else          run_l1(c01, out, ws, bid - 64, &smem[0][0][0]);
}

extern "C" void kernel_launch(void* const* d_in, const int* in_sizes, int n_in,
                              void* d_out, int out_size, void* d_ws, size_t ws_size,
                              hipStream_t stream) {
    const float* x    = (const float*)d_in[0];
    const float* h0_0 = (const float*)d_in[1];
    const float* c0_0 = (const float*)d_in[2];
    const float* h0_1 = (const float*)d_in[3];
    const float* c0_1 = (const float*)d_in[4];
    const float* Wih0 = (const float*)d_in[5];
    const float* Whh0 = (const float*)d_in[6];
    const float* bih0 = (const float*)d_in[7];
    const float* bhh0 = (const float*)d_in[8];
    const float* Wih1 = (const float*)d_in[9];
    const float* Whh1 = (const float*)d_in[10];
    const float* bih1 = (const float*)d_in[11];
    const float* bhh1 = (const float*)d_in[12];
    float* out = (float*)d_out;
    unsigned char* ws = (unsigned char*)d_ws;

    k_init<<<128, 256, 0, stream>>>(bih0, bhh0, bih1, bhh1, h0_0, h0_1, ws);
    k_wprep<<<1792, 256, 0, stream>>>(Wih0, Whh0, Wih1, Whh1, ws);
    k_lstm<<<128, 256, 0, stream>>>(x, c0_0, c0_1, out, ws);
}